// Round 2
// baseline (49.724 us; speedup 1.0000x reference)
//
#include <hip/hip_runtime.h>

#define BB 4
#define NN 512
#define HH 64
#define NODES (BB*NN)
#define SPLIT 4
#define JCH (NN/SPLIT)   // j's per slice = 128

typedef float v4f __attribute__((ext_vector_type(4)));

// ---------------- Kernel A: encoder MLP + message projections ----------------
// one wave (64 threads) per node; lane k owns output dim k.
// aj is written TRANSPOSED: ajT[(b*HH + k)*NN + n] so pair_kernel lanes can
// read 4 consecutive j's with one dwordx4.
__global__ __launch_bounds__(64) void enc_kernel(
    const float* __restrict__ pos,
    const float* __restrict__ enc_w1, const float* __restrict__ enc_b1,
    const float* __restrict__ enc_w2, const float* __restrict__ enc_b2,
    const float* __restrict__ msg_w1,
    float* __restrict__ h_out, float* __restrict__ ai_out, float* __restrict__ ajT_out)
{
    const int node = blockIdx.x;
    const int k = threadIdx.x;
    const int b = node >> 9;        // node / NN
    const int n = node & (NN-1);    // node % NN
    __shared__ float t_s[HH];
    __shared__ float h_s[HH];

    const float px = pos[node*2+0];
    const float py = pos[node*2+1];

    // layer 1: relu(pos @ enc_w1 + enc_b1)
    float t = fmaf(px, enc_w1[k], fmaf(py, enc_w1[HH + k], enc_b1[k]));
    t_s[k] = fmaxf(t, 0.f);
    __syncthreads();

    // layer 2: h = t @ enc_w2 + enc_b2
    float h = enc_b2[k];
    #pragma unroll
    for (int m = 0; m < HH; ++m) h = fmaf(t_s[m], enc_w2[m*HH + k], h);
    h_s[k] = h;
    h_out[node*HH + k] = h;
    __syncthreads();

    // a_i = h @ msg_w1[:64],  a_j = h @ msg_w1[64:128]
    float ai = 0.f, aj = 0.f;
    #pragma unroll
    for (int m = 0; m < HH; ++m) {
        const float hm = h_s[m];
        ai = fmaf(hm, msg_w1[m*HH + k],        ai);
        aj = fmaf(hm, msg_w1[(HH + m)*HH + k], aj);
    }
    ai_out[node*HH + k] = ai;
    ajT_out[(size_t)(b*HH + k)*NN + n] = aj;
}

// ---------------- Kernel B: pairwise relu-accumulate ----------------
// block = 256 threads = 4 waves; wave w handles node i = igrp*4 + w, and this
// block covers j-slice s (SPLIT-way j split for occupancy). Per-wave distance
// buffer in LDS (no barriers needed: wave-internal LDS RAW is instruction-
// ordered). Inner loop is float4-vectorized: 1 dwordx4 aj load + 1 b128 LDS
// broadcast + packed fma/max per 4 elements.
__global__ __launch_bounds__(256) void pair_kernel(
    const float* __restrict__ pos, const int* __restrict__ box_ptr,
    const float* __restrict__ msg_w1, const float* __restrict__ msg_b1,
    const float* __restrict__ ai, const float* __restrict__ ajT,
    float* __restrict__ acc_part)
{
    const int w = threadIdx.x >> 6;
    const int k = threadIdx.x & 63;
    const int bid = blockIdx.x;
    const int s   = bid >> 9;          // bid / (NODES/4)   (NODES/4 = 512)
    const int rem = bid & 511;
    const int b    = rem >> 7;
    const int igrp = rem & 127;
    const int i = igrp*4 + w;
    const int node = b*NN + i;

    const float box  = (float)box_ptr[0];
    const float hbox = 0.5f * box;

    __shared__ v4f dbuf4[4][16];
    float* dbuf = (float*)dbuf4[w];

    const float2* pos2 = (const float2*)pos;
    const float2 pi = pos2[node];
    const float base = ai[node*HH + k] + msg_b1[k];
    const float wd   = msg_w1[2*HH*HH + k];
    const float* rowp = ajT + (size_t)(b*HH + k)*NN;

    v4f acc4 = {0.f, 0.f, 0.f, 0.f};
    #pragma unroll
    for (int c = 0; c < JCH/64; ++c) {
        const int j0 = s*JCH + c*64;
        // lane k computes the distance for j = j0 + k
        {
            const float2 pj = pos2[b*NN + j0 + k];
            float dx = pj.x - pi.x;
            float dy = pj.y - pi.y;
            // minimum image: |dx| < box -> round(dx/box) in {-1,0,1}
            dx -= (dx >  hbox) ? box : 0.f;
            dx += (dx < -hbox) ? box : 0.f;
            dy -= (dy >  hbox) ? box : 0.f;
            dy += (dy < -hbox) ? box : 0.f;
            dbuf[k] = sqrtf(fmaf(dx, dx, dy*dy));
        }
        __builtin_amdgcn_wave_barrier();   // keep compiler from reordering

        const v4f* a4p = (const v4f*)(rowp + j0);
        #pragma unroll
        for (int q = 0; q < 16; ++q) {
            const v4f d4 = dbuf4[w][q];    // uniform address -> LDS broadcast
            const v4f a4 = a4p[q];         // 16B per lane, own row
            v4f t = __builtin_elementwise_fma(d4, (v4f)(wd), a4 + (v4f)(base));
            acc4 += __builtin_elementwise_max(t, (v4f){0.f,0.f,0.f,0.f});
        }
        __builtin_amdgcn_wave_barrier();
    }
    float acc = (acc4.x + acc4.y) + (acc4.z + acc4.w);

    // remove j == i contribution if i falls in this slice (d == 0 exactly,
    // fmaf(0,wd,x) == x, so the in-loop term was exactly relu(base + aj_ii))
    if (i >= s*JCH && i < (s+1)*JCH) {
        acc -= fmaxf(base + rowp[i], 0.f);
    }
    acc_part[((size_t)s*NODES + node)*HH + k] = acc;
}

// ---------------- Kernel C: aggregate matmul + update MLP + decoder ----------------
__global__ __launch_bounds__(64) void out_kernel(
    const float* __restrict__ h_in, const float* __restrict__ acc_in,
    const float* __restrict__ msg_w2, const float* __restrict__ msg_b2,
    const float* __restrict__ upd_w1, const float* __restrict__ upd_b1,
    const float* __restrict__ upd_w2, const float* __restrict__ upd_b2,
    const float* __restrict__ dec_w1, const float* __restrict__ dec_b1,
    const float* __restrict__ dec_w2, const float* __restrict__ dec_b2,
    float* __restrict__ out)
{
    const int node = blockIdx.x;
    const int k = threadIdx.x;
    __shared__ float acc_s[HH], h_s[HH], agg_s[HH], p_s[HH], u_s[HH];

    float a = 0.f;
    #pragma unroll
    for (int sl = 0; sl < SPLIT; ++sl)
        a += acc_in[((size_t)sl*NODES + node)*HH + k];
    acc_s[k] = a;
    h_s[k]   = h_in[node*HH + k];
    __syncthreads();

    // agg = (acc @ msg_w2) / (N-1) + msg_b2
    const float inv = 1.f / (float)(NN - 1);
    float agg = 0.f;
    #pragma unroll
    for (int m = 0; m < HH; ++m) agg = fmaf(acc_s[m], msg_w2[m*HH + k], agg);
    agg = fmaf(agg, inv, msg_b2[k]);
    agg_s[k] = agg;
    __syncthreads();

    // u = relu([h, agg] @ upd_w1 + upd_b1) @ upd_w2 + upd_b2
    float p = upd_b1[k];
    #pragma unroll
    for (int m = 0; m < HH; ++m) p = fmaf(h_s[m],   upd_w1[m*HH + k],        p);
    #pragma unroll
    for (int m = 0; m < HH; ++m) p = fmaf(agg_s[m], upd_w1[(HH + m)*HH + k], p);
    p_s[k] = fmaxf(p, 0.f);
    __syncthreads();

    float u = upd_b2[k];
    #pragma unroll
    for (int m = 0; m < HH; ++m) u = fmaf(p_s[m], upd_w2[m*HH + k], u);
    u_s[k] = u;
    __syncthreads();

    // forces = relu(u @ dec_w1 + dec_b1) @ dec_w2 + dec_b2
    float d1 = dec_b1[k];
    #pragma unroll
    for (int m = 0; m < HH; ++m) d1 = fmaf(u_s[m], dec_w1[m*HH + k], d1);
    d1 = fmaxf(d1, 0.f);

    float f0 = d1 * dec_w2[k*2 + 0];
    float f1 = d1 * dec_w2[k*2 + 1];
    #pragma unroll
    for (int off = 32; off >= 1; off >>= 1) {
        f0 += __shfl_xor(f0, off, 64);
        f1 += __shfl_xor(f1, off, 64);
    }
    if (k == 0) {
        out[node*2 + 0] = f0 + dec_b2[0];
        out[node*2 + 1] = f1 + dec_b2[1];
    }
}

extern "C" void kernel_launch(void* const* d_in, const int* in_sizes, int n_in,
                              void* d_out, int out_size, void* d_ws, size_t ws_size,
                              hipStream_t stream) {
    const float* pos    = (const float*)d_in[0];
    const int*   boxp   = (const int*)  d_in[1];
    const float* enc_w1 = (const float*)d_in[2];
    const float* enc_b1 = (const float*)d_in[3];
    const float* enc_w2 = (const float*)d_in[4];
    const float* enc_b2 = (const float*)d_in[5];
    const float* msg_w1 = (const float*)d_in[6];
    const float* msg_b1 = (const float*)d_in[7];
    const float* msg_w2 = (const float*)d_in[8];
    const float* msg_b2 = (const float*)d_in[9];
    const float* upd_w1 = (const float*)d_in[10];
    const float* upd_b1 = (const float*)d_in[11];
    const float* upd_w2 = (const float*)d_in[12];
    const float* upd_b2 = (const float*)d_in[13];
    const float* dec_w1 = (const float*)d_in[14];
    const float* dec_b1 = (const float*)d_in[15];
    const float* dec_w2 = (const float*)d_in[16];
    const float* dec_b2 = (const float*)d_in[17];

    float* ws   = (float*)d_ws;
    float* h    = ws;
    float* ai   = ws + (size_t)NODES*HH;
    float* ajT  = ws + (size_t)2*NODES*HH;
    float* accp = ws + (size_t)3*NODES*HH;   // SPLIT * NODES * HH floats

    enc_kernel<<<NODES, 64, 0, stream>>>(pos, enc_w1, enc_b1, enc_w2, enc_b2,
                                         msg_w1, h, ai, ajT);
    pair_kernel<<<(NODES/4)*SPLIT, 256, 0, stream>>>(pos, boxp, msg_w1, msg_b1,
                                                     ai, ajT, accp);
    out_kernel<<<NODES, 64, 0, stream>>>(h, accp, msg_w2, msg_b2,
                                         upd_w1, upd_b1, upd_w2, upd_b2,
                                         dec_w1, dec_b1, dec_w2, dec_b2,
                                         (float*)d_out);
}

// Round 3
// 29.741 us; speedup vs baseline: 1.6719x; 1.6719x over previous
//
#include <hip/hip_runtime.h>

#define BB 4
#define NN 512
#define HH 64
#define NODES (BB*NN)
#define SPLIT 8
#define JCH (NN/SPLIT)   // 64 j's per slice
#define TI 4             // i's per wave

typedef float v4f __attribute__((ext_vector_type(4)));

// ---------------- Kernel A: encoder MLP + message projections ----------------
// one wave (64 threads) per node; lane k owns output dim k. aj in [node][k]
// layout (coalesced both when written here and when read 1KB/instr in pair).
__global__ __launch_bounds__(64) void enc_kernel(
    const float* __restrict__ pos,
    const float* __restrict__ enc_w1, const float* __restrict__ enc_b1,
    const float* __restrict__ enc_w2, const float* __restrict__ enc_b2,
    const float* __restrict__ msg_w1,
    float* __restrict__ h_out, float* __restrict__ ai_out, float* __restrict__ aj_out)
{
    const int node = blockIdx.x;
    const int k = threadIdx.x;
    __shared__ float t_s[HH];
    __shared__ float h_s[HH];

    const float px = pos[node*2+0];
    const float py = pos[node*2+1];

    float t = fmaf(px, enc_w1[k], fmaf(py, enc_w1[HH + k], enc_b1[k]));
    t_s[k] = fmaxf(t, 0.f);
    __syncthreads();

    float h = enc_b2[k];
    #pragma unroll
    for (int m = 0; m < HH; ++m) h = fmaf(t_s[m], enc_w2[m*HH + k], h);
    h_s[k] = h;
    h_out[node*HH + k] = h;
    __syncthreads();

    float ai = 0.f, aj = 0.f;
    #pragma unroll
    for (int m = 0; m < HH; ++m) {
        const float hm = h_s[m];
        ai = fmaf(hm, msg_w1[m*HH + k],        ai);
        aj = fmaf(hm, msg_w1[(HH + m)*HH + k], aj);
    }
    ai_out[node*HH + k] = ai;
    aj_out[node*HH + k] = aj;
}

// ---------------- Kernel B: pairwise relu-accumulate ----------------
// Wave-job = (i-group of TI=4 nodes) x (j-slice of JCH=64 nodes).
// Lane l: jgrp = l>>4 (which of 4 consecutive j rows), kq = l&15 (k-quad).
// Per iteration: one dwordx4 of aj (1024B contiguous across the wave) feeds
// TI accumulators; distances come from a per-wave LDS buffer arranged so each
// lane's 16 per-i distances are contiguous (ds_read_b128, broadcast, <=2-way).
__global__ __launch_bounds__(256) void pair_kernel(
    const float* __restrict__ pos, const int* __restrict__ box_ptr,
    const float* __restrict__ msg_w1, const float* __restrict__ msg_b1,
    const float* __restrict__ ai, const float* __restrict__ aj,
    float* __restrict__ acc_part)
{
    const int w  = threadIdx.x >> 6;
    const int l  = threadIdx.x & 63;
    const int jgrp = l >> 4;
    const int kq   = l & 15;
    const int wj = blockIdx.x*4 + w;          // wave-job id
    const int s  = wj & (SPLIT-1);            // j-slice
    const int ig = wj >> 3;                   // i-group 0..511
    const int b  = ig >> 7;                   // batch (128 groups/batch)
    const int i0 = (ig & 127) * TI;           // local i base
    const int jch0 = s * JCH;                 // j base within batch

    const float box  = (float)box_ptr[0];
    const float hbox = 0.5f * box;

    __shared__ float dbuf[4][TI*64];          // per wave: TI x 64 dist slots
    float* db = dbuf[w];

    const float2* pos2 = (const float2*)pos;

    // prologue: per-lane k-quad params, per-i bases
    const v4f wd4 = *(const v4f*)(msg_w1 + 2*HH*HH + 4*kq);
    const v4f b1  = *(const v4f*)(msg_b1 + 4*kq);
    v4f base4[TI];
    float2 pi[TI];
    #pragma unroll
    for (int ii = 0; ii < TI; ++ii) {
        const int node = b*NN + i0 + ii;
        base4[ii] = *(const v4f*)(ai + (size_t)node*HH + 4*kq) + b1;
        pi[ii] = pos2[node];
    }

    // distance phase: lane l handles j = jch0 + l, all TI i's.
    // slot layout: db[ii*64 + (o&3)*16 + (o>>2)] so that read at iteration
    // t (o = t*4+jgrp) is contiguous v4 per t4-group.
    {
        const float2 pj = pos2[b*NN + jch0 + l];
        #pragma unroll
        for (int ii = 0; ii < TI; ++ii) {
            float dx = pj.x - pi[ii].x;
            float dy = pj.y - pi[ii].y;
            dx -= (dx >  hbox) ? box : 0.f;
            dx += (dx < -hbox) ? box : 0.f;
            dy -= (dy >  hbox) ? box : 0.f;
            dy += (dy < -hbox) ? box : 0.f;
            db[ii*64 + (l&3)*16 + (l>>2)] = sqrtf(fmaf(dx, dx, dy*dy));
        }
    }
    __builtin_amdgcn_wave_barrier();   // per-wave buffer; lgkmcnt orders RAW

    v4f acc[TI];
    #pragma unroll
    for (int ii = 0; ii < TI; ++ii) acc[ii] = (v4f){0.f,0.f,0.f,0.f};

    #pragma unroll
    for (int t4 = 0; t4 < 4; ++t4) {
        v4f d4[TI];
        #pragma unroll
        for (int ii = 0; ii < TI; ++ii)
            d4[ii] = *(const v4f*)(db + ii*64 + jgrp*16 + 4*t4);
        #pragma unroll
        for (int u = 0; u < 4; ++u) {
            const int o = (t4*4 + u)*4 + jgrp;          // j offset in slice
            const v4f a4 = *(const v4f*)(aj + (size_t)(b*NN + jch0 + o)*HH + 4*kq);
            #pragma unroll
            for (int ii = 0; ii < TI; ++ii) {
                const float d = d4[ii][u];
                v4f t = __builtin_elementwise_fma((v4f)(d), wd4, a4 + base4[ii]);
                acc[ii] += __builtin_elementwise_max(t, (v4f){0.f,0.f,0.f,0.f});
            }
        }
    }

    // reduce partials across the 4 jgrp lane-groups (lanes l, l^16, l^32)
    #pragma unroll
    for (int ii = 0; ii < TI; ++ii) {
        #pragma unroll
        for (int c = 0; c < 4; ++c) {
            float v = acc[ii][c];
            v += __shfl_xor(v, 16, 64);
            v += __shfl_xor(v, 32, 64);
            acc[ii][c] = v;
        }
    }

    // writer: lane l writes ii = jgrp at its kq; subtract exact self-term if
    // i falls in this j-slice (d_ii == 0 exactly -> in-loop term == relu(base+aj_i))
    {
        const int ii = jgrp;
        const int i  = i0 + ii;
        v4f a = acc[ii];
        if ((i >> 6) == s) {
            const v4f ajs = *(const v4f*)(aj + (size_t)(b*NN + i)*HH + 4*kq);
            v4f t = base4[ii] + ajs;
            a -= __builtin_elementwise_max(t, (v4f){0.f,0.f,0.f,0.f});
        }
        *(v4f*)(acc_part + ((size_t)s*NODES + b*NN + i)*HH + 4*kq) = a;
    }
}

// ---------------- Kernel C: aggregate matmul + update MLP + decoder ----------------
__global__ __launch_bounds__(64) void out_kernel(
    const float* __restrict__ h_in, const float* __restrict__ acc_in,
    const float* __restrict__ msg_w2, const float* __restrict__ msg_b2,
    const float* __restrict__ upd_w1, const float* __restrict__ upd_b1,
    const float* __restrict__ upd_w2, const float* __restrict__ upd_b2,
    const float* __restrict__ dec_w1, const float* __restrict__ dec_b1,
    const float* __restrict__ dec_w2, const float* __restrict__ dec_b2,
    float* __restrict__ out)
{
    const int node = blockIdx.x;
    const int k = threadIdx.x;
    __shared__ float acc_s[HH], h_s[HH], agg_s[HH], p_s[HH], u_s[HH];

    float a = 0.f;
    #pragma unroll
    for (int sl = 0; sl < SPLIT; ++sl)
        a += acc_in[((size_t)sl*NODES + node)*HH + k];
    acc_s[k] = a;
    h_s[k]   = h_in[node*HH + k];
    __syncthreads();

    const float inv = 1.f / (float)(NN - 1);
    float agg = 0.f;
    #pragma unroll
    for (int m = 0; m < HH; ++m) agg = fmaf(acc_s[m], msg_w2[m*HH + k], agg);
    agg = fmaf(agg, inv, msg_b2[k]);
    agg_s[k] = agg;
    __syncthreads();

    float p = upd_b1[k];
    #pragma unroll
    for (int m = 0; m < HH; ++m) p = fmaf(h_s[m],   upd_w1[m*HH + k],        p);
    #pragma unroll
    for (int m = 0; m < HH; ++m) p = fmaf(agg_s[m], upd_w1[(HH + m)*HH + k], p);
    p_s[k] = fmaxf(p, 0.f);
    __syncthreads();

    float u = upd_b2[k];
    #pragma unroll
    for (int m = 0; m < HH; ++m) u = fmaf(p_s[m], upd_w2[m*HH + k], u);
    u_s[k] = u;
    __syncthreads();

    float d1 = dec_b1[k];
    #pragma unroll
    for (int m = 0; m < HH; ++m) d1 = fmaf(u_s[m], dec_w1[m*HH + k], d1);
    d1 = fmaxf(d1, 0.f);

    float f0 = d1 * dec_w2[k*2 + 0];
    float f1 = d1 * dec_w2[k*2 + 1];
    #pragma unroll
    for (int off = 32; off >= 1; off >>= 1) {
        f0 += __shfl_xor(f0, off, 64);
        f1 += __shfl_xor(f1, off, 64);
    }
    if (k == 0) {
        out[node*2 + 0] = f0 + dec_b2[0];
        out[node*2 + 1] = f1 + dec_b2[1];
    }
}

extern "C" void kernel_launch(void* const* d_in, const int* in_sizes, int n_in,
                              void* d_out, int out_size, void* d_ws, size_t ws_size,
                              hipStream_t stream) {
    const float* pos    = (const float*)d_in[0];
    const int*   boxp   = (const int*)  d_in[1];
    const float* enc_w1 = (const float*)d_in[2];
    const float* enc_b1 = (const float*)d_in[3];
    const float* enc_w2 = (const float*)d_in[4];
    const float* enc_b2 = (const float*)d_in[5];
    const float* msg_w1 = (const float*)d_in[6];
    const float* msg_b1 = (const float*)d_in[7];
    const float* msg_w2 = (const float*)d_in[8];
    const float* msg_b2 = (const float*)d_in[9];
    const float* upd_w1 = (const float*)d_in[10];
    const float* upd_b1 = (const float*)d_in[11];
    const float* upd_w2 = (const float*)d_in[12];
    const float* upd_b2 = (const float*)d_in[13];
    const float* dec_w1 = (const float*)d_in[14];
    const float* dec_b1 = (const float*)d_in[15];
    const float* dec_w2 = (const float*)d_in[16];
    const float* dec_b2 = (const float*)d_in[17];

    float* ws   = (float*)d_ws;
    float* h    = ws;
    float* ai   = ws + (size_t)NODES*HH;
    float* aj   = ws + (size_t)2*NODES*HH;
    float* accp = ws + (size_t)3*NODES*HH;   // SPLIT * NODES * HH floats

    enc_kernel<<<NODES, 64, 0, stream>>>(pos, enc_w1, enc_b1, enc_w2, enc_b2,
                                         msg_w1, h, ai, aj);
    pair_kernel<<<(NODES/TI)*SPLIT/4, 256, 0, stream>>>(pos, boxp, msg_w1, msg_b1,
                                                        ai, aj, accp);
    out_kernel<<<NODES, 64, 0, stream>>>(h, accp, msg_w2, msg_b2,
                                         upd_w1, upd_b1, upd_w2, upd_b2,
                                         dec_w1, dec_b1, dec_w2, dec_b2,
                                         (float*)d_out);
}